// Round 1
// baseline (62.043 us; speedup 1.0000x reference)
//
#include <hip/hip_runtime.h>
#include <hip/hip_bf16.h>

// LogicConv3d: B=64, C=32, H=32, W=32, K=64, P=28*28=784, S=16 gathers per side.
// Tree: 16 -> 8 -> 4 -> 2 -> 1 soft binary ops with softmax(w)·COEF coefficients.

#define B_  64
#define C_  32
#define H_  32
#define W_  32
#define K_  64
#define P_  784
#define CHW (C_*H_*W_)      // 32768
#define HW  (H_*W_)         // 1024

__constant__ float COEF_[16][4] = {
    {0, 0, 0, 0}, {0, 0, 0, 1}, {0, 1, 0, -1}, {0, 1, 0, 0},
    {0, 0, 1, -1}, {0, 0, 1, 0}, {0, 1, 1, -2}, {0, 1, 1, -1},
    {1, -1, -1, 1}, {1, -1, -1, 2}, {1, 0, -1, 0}, {1, 0, -1, 1},
    {1, -1, 0, 0}, {1, -1, 0, 1}, {1, 0, 0, -1}, {1, 0, 0, 0}
};

#define BCHUNK 16

__global__ __launch_bounds__(256) void logicconv_kernel(
    const float* __restrict__ x,
    const float* __restrict__ w0, const float* __restrict__ w1,
    const float* __restrict__ w2, const float* __restrict__ w3,
    const float* __restrict__ w4,
    const int* __restrict__ a_idx, const int* __restrict__ b_idx,
    float* __restrict__ out)
{
    __shared__ float4 sc[31];   // coefs: L0 at [0..15], L1 [16..23], L2 [24..27], L3 [28..29], L4 [30]

    const int tid = threadIdx.x;
    const int k   = blockIdx.y;

    // ---- block prologue: 31 threads compute softmax(w)·COEF for this k ----
    if (tid < 31) {
        int d, l;
        if      (tid < 16) { d = 0; l = tid; }
        else if (tid < 24) { d = 1; l = tid - 16; }
        else if (tid < 28) { d = 2; l = tid - 24; }
        else if (tid < 30) { d = 3; l = tid - 28; }
        else               { d = 4; l = 0; }
        const float* W;
        switch (d) {
            case 0: W = w0; break;
            case 1: W = w1; break;
            case 2: W = w2; break;
            case 3: W = w3; break;
            default: W = w4; break;
        }
        const float* row = W + ((size_t)l * K_ + k) * 16;
        float m = row[0];
        #pragma unroll
        for (int o = 1; o < 16; ++o) m = fmaxf(m, row[o]);
        float e[16];
        float Z = 0.0f;
        #pragma unroll
        for (int o = 0; o < 16; ++o) { e[o] = expf(row[o] - m); Z += e[o]; }
        const float inv = 1.0f / Z;
        float c0 = 0.f, c1 = 0.f, c2 = 0.f, c3 = 0.f;
        #pragma unroll
        for (int o = 0; o < 16; ++o) {
            c0 += e[o] * COEF_[o][0];
            c1 += e[o] * COEF_[o][1];
            c2 += e[o] * COEF_[o][2];
            c3 += e[o] * COEF_[o][3];
        }
        sc[tid] = make_float4(c0 * inv, c1 * inv, c2 * inv, c3 * inv);
    }
    __syncthreads();

    const int p = blockIdx.x * 256 + tid;
    if (p >= P_) return;   // no further barriers

    // ---- offsets (batch-independent): 16 A + 16 B flat offsets into one image ----
    int offA[16], offB[16];
    const size_t ib = ((size_t)(k * P_ + p)) * 48;   // 16 * 3 ints
    #pragma unroll
    for (int l = 0; l < 16; ++l) {
        const int ha = a_idx[ib + l*3 + 0];
        const int wa = a_idx[ib + l*3 + 1];
        const int ca = a_idx[ib + l*3 + 2];
        offA[l] = ca * HW + ha * W_ + wa;
        const int hb = b_idx[ib + l*3 + 0];
        const int wb = b_idx[ib + l*3 + 1];
        const int cb = b_idx[ib + l*3 + 2];
        offB[l] = cb * HW + hb * W_ + wb;
    }

    const int b0 = blockIdx.z * BCHUNK;
    for (int b = b0; b < b0 + BCHUNK; ++b) {
        const float* __restrict__ xb = x + (size_t)b * CHW;
        float va[16], vb[16];
        #pragma unroll
        for (int l = 0; l < 16; ++l) {
            va[l] = xb[offA[l]];
            vb[l] = xb[offB[l]];
        }
        float y[16];
        // layer 0: 16 outputs from (a,b) pairs
        #pragma unroll
        for (int l = 0; l < 16; ++l) {
            const float4 c = sc[l];
            y[l] = fmaf(c.w, va[l] * vb[l], fmaf(c.z, vb[l], fmaf(c.y, va[l], c.x)));
        }
        // layer 1: 8
        #pragma unroll
        for (int l = 0; l < 8; ++l) {
            const float4 c = sc[16 + l];
            const float a = y[2*l], bb = y[2*l + 1];
            y[l] = fmaf(c.w, a * bb, fmaf(c.z, bb, fmaf(c.y, a, c.x)));
        }
        // layer 2: 4
        #pragma unroll
        for (int l = 0; l < 4; ++l) {
            const float4 c = sc[24 + l];
            const float a = y[2*l], bb = y[2*l + 1];
            y[l] = fmaf(c.w, a * bb, fmaf(c.z, bb, fmaf(c.y, a, c.x)));
        }
        // layer 3: 2
        #pragma unroll
        for (int l = 0; l < 2; ++l) {
            const float4 c = sc[28 + l];
            const float a = y[2*l], bb = y[2*l + 1];
            y[l] = fmaf(c.w, a * bb, fmaf(c.z, bb, fmaf(c.y, a, c.x)));
        }
        // layer 4: 1
        {
            const float4 c = sc[30];
            const float a = y[0], bb = y[1];
            y[0] = fmaf(c.w, a * bb, fmaf(c.z, bb, fmaf(c.y, a, c.x)));
        }
        out[((size_t)b * K_ + k) * P_ + p] = y[0];
    }
}

extern "C" void kernel_launch(void* const* d_in, const int* in_sizes, int n_in,
                              void* d_out, int out_size, void* d_ws, size_t ws_size,
                              hipStream_t stream) {
    const float* x    = (const float*)d_in[0];
    const float* w0   = (const float*)d_in[1];
    const float* w1   = (const float*)d_in[2];
    const float* w2   = (const float*)d_in[3];
    const float* w3   = (const float*)d_in[4];
    const float* w4   = (const float*)d_in[5];
    const int*   a_idx = (const int*)d_in[6];
    const int*   b_idx = (const int*)d_in[7];
    float* out = (float*)d_out;

    dim3 grid((P_ + 255) / 256, K_, B_ / BCHUNK);
    logicconv_kernel<<<grid, 256, 0, stream>>>(x, w0, w1, w2, w3, w4,
                                               a_idx, b_idx, out);
}